// Round 5
// baseline (129.670 us; speedup 1.0000x reference)
//
#include <hip/hip_runtime.h>

typedef float f32x4 __attribute__((ext_vector_type(4)));

// Problem constants: x [B,C,T] fp32 -> out [B,C,T] fp32.
#define B_ 32
#define C_ 256
#define T_ 2048
#define CHUNK 64
#define K_ 32          // chunks per row
#define LOOK 64        // warm-start lookback (bitwise-exact, proven R2/R3)

// One thread per (row, chunk). 4 phases x 32 elements = LOOK + CHUNK.
// Triple-buffered register pipeline + full-line (128 B) burst stores.

#define STEP(X0, XP1, O) { \
    float y = w0 * xm1;  y = y + w1 * (X0);  y = y + w2 * (XP1); \
    y = y + bb;  y = y * inv;  y = y + add; \
    float dv = (y - v) * 0.5f;  v = v + dv; \
    float s = (v >= 1.0f) ? 1.0f : 0.0f; \
    (O) = s + (X0); \
    v = (v >= 1.0f) ? 0.0f : v; \
    xm1 = (X0); }

#define Q4(BV, NX, O) \
    STEP(BV.x, BV.y, O.x) STEP(BV.y, BV.z, O.y) \
    STEP(BV.z, BV.w, O.z) STEP(BV.w, NX,   O.w)

// compute 32 elems from r0..r7; PEEK = x[tp+32]; optional full-line store burst
#define PHASE32(r0,r1,r2,r3,r4,r5,r6,r7, PEEK, TP, DOSTORE) { \
    f32x4 o0,o1,o2,o3,o4,o5,o6,o7; \
    Q4(r0, r1.x, o0) Q4(r1, r2.x, o1) Q4(r2, r3.x, o2) Q4(r3, r4.x, o3) \
    Q4(r4, r5.x, o4) Q4(r5, r6.x, o5) Q4(r6, r7.x, o6) Q4(r7, PEEK, o7) \
    if (DOSTORE) { \
        f32x4* _q = (f32x4*)(outr + (TP)); \
        __builtin_nontemporal_store(o0, _q + 0); \
        __builtin_nontemporal_store(o1, _q + 1); \
        __builtin_nontemporal_store(o2, _q + 2); \
        __builtin_nontemporal_store(o3, _q + 3); \
        __builtin_nontemporal_store(o4, _q + 4); \
        __builtin_nontemporal_store(o5, _q + 5); \
        __builtin_nontemporal_store(o6, _q + 6); \
        __builtin_nontemporal_store(o7, _q + 7); } }

// load one 32-elem phase (8 x float4); TP < 0 (k==0 lookback) -> zeros
#define LOADPH(r0,r1,r2,r3,r4,r5,r6,r7, TP) \
    if ((TP) >= 0) { const f32x4* _p = xr4 + ((TP) >> 2); \
        r0=_p[0]; r1=_p[1]; r2=_p[2]; r3=_p[3]; \
        r4=_p[4]; r5=_p[5]; r6=_p[6]; r7=_p[7]; } \
    else { r0=Z; r1=Z; r2=Z; r3=Z; r4=Z; r5=Z; r6=Z; r7=Z; }

__global__ __launch_bounds__(256) void cpe_lif_kernel(
    const float* __restrict__ x, const float* __restrict__ w,
    const float* __restrict__ cb, const float* __restrict__ gamma,
    const float* __restrict__ beta, const float* __restrict__ rmean,
    const float* __restrict__ rvar, float* __restrict__ out)
{
#pragma clang fp contract(off)   // match np reference rounding op-for-op
    const int u   = blockIdx.x * blockDim.x + threadIdx.x;
    const int row = u >> 5;          // / K_
    const int k   = u & (K_ - 1);
    const int ch  = row & (C_ - 1);

    // Per-channel constants, numpy-port op order (all fp32, correctly rounded).
    const float w0 = w[ch * 3 + 0], w1 = w[ch * 3 + 1], w2 = w[ch * 3 + 2];
    const float bb = cb[ch];
    const float sq  = sqrtf(rvar[ch] + 1e-5f);
    const float rs  = 1.0f / sq;
    const float inv = gamma[ch] * rs;
    const float add = beta[ch] - rmean[ch] * inv;

    const float*  xr  = x + (size_t)row * T_;
    const f32x4*  xr4 = (const f32x4*)xr;
    float* outr = out + (size_t)row * T_;

    const int t0 = k * CHUNK;
    const int ts = t0 - LOOK;            // <= 0 for k in {0,1}

    // Conv left halo: ts <= 0 means the lookback window starts at (or before)
    // t=0, whose true halo is the zero pad. (ts==0 happened only at k==1;
    // reading xr[-1] here was R4's OOB crash.)
    float xm1 = (ts <= 0) ? 0.0f : xr[ts - 1];
    const float xn = (k == K_ - 1) ? 0.0f : xr[t0 + CHUNK];    // right halo peek
    float v = 0.0f;

    f32x4 Z; Z.x = Z.y = Z.z = Z.w = 0.0f;
    f32x4 a0,a1,a2,a3,a4,a5,a6,a7;
    f32x4 b0,b1,b2,b3,b4,b5,b6,b7;
    f32x4 d0,d1,d2,d3,d4,d5,d6,d7;

    // Prologue: 3 phases of loads in flight (96 elements).
    LOADPH(a0,a1,a2,a3,a4,a5,a6,a7, ts)        // P0 (lookback)
    LOADPH(b0,b1,b2,b3,b4,b5,b6,b7, ts + 32)   // P1 (lookback)
    LOADPH(d0,d1,d2,d3,d4,d5,d6,d7, t0)        // P2 (output)

    // P0 (lookback, no store; k==0 skips: zeros, v must stay 0)
    if (k > 0) { PHASE32(a0,a1,a2,a3,a4,a5,a6,a7, b0.x, ts, false) }
    LOADPH(a0,a1,a2,a3,a4,a5,a6,a7, t0 + 32)   // P3 -> A

    // P1 (lookback, no store)
    if (k > 0) { PHASE32(b0,b1,b2,b3,b4,b5,b6,b7, d0.x, ts + 32, false) }

    // P2, P3 (t = t0 .. t0+63): store
    PHASE32(d0,d1,d2,d3,d4,d5,d6,d7, a0.x, t0,      true)
    PHASE32(a0,a1,a2,a3,a4,a5,a6,a7, xn,   t0 + 32, true)
}

extern "C" void kernel_launch(void* const* d_in, const int* in_sizes, int n_in,
                              void* d_out, int out_size, void* d_ws, size_t ws_size,
                              hipStream_t stream) {
    const float* x     = (const float*)d_in[0];
    const float* w     = (const float*)d_in[1];
    const float* cb    = (const float*)d_in[2];
    const float* gamma = (const float*)d_in[3];
    const float* beta  = (const float*)d_in[4];
    const float* rmean = (const float*)d_in[5];
    const float* rvar  = (const float*)d_in[6];
    float* out = (float*)d_out;

    const int total = B_ * C_ * K_;                    // 262144 threads
    const int block = 256;
    const int grid  = (total + block - 1) / block;     // 1024 blocks -> 4 wg/CU
    cpe_lif_kernel<<<grid, block, 0, stream>>>(x, w, cb, gamma, beta, rmean, rvar, out);
}

// Round 6
// 47.205 us; speedup vs baseline: 2.7470x; 2.7470x over previous
//
#include <hip/hip_runtime.h>

typedef float f32x4 __attribute__((ext_vector_type(4)));

// Problem constants: x [B,C,T] fp32 -> out [B,C,T] fp32.
#define B_ 32
#define C_ 256
#define T_ 2048
#define CHUNK 64
#define K_ 32          // chunks per row
#define LOOK 64        // warm-start lookback (bitwise-exact, proven R2/R3/R5)

// One thread per (row, chunk). 4 phases x 32 elements = LOOK + CHUNK.
// Triple-buffered register pipeline + full-line (128 B) burst stores.
// NOTE (R5 lesson): plain stores, NOT nontemporal — L2 write-combining is
// what merges the 16 B/lane bursts into full-line HBM evictions; `nt`
// bypassed it and caused 3.3x write amplification.

#define STEP(X0, XP1, O) { \
    float y = w0 * xm1;  y = y + w1 * (X0);  y = y + w2 * (XP1); \
    y = y + bb;  y = y * inv;  y = y + add; \
    float dv = (y - v) * 0.5f;  v = v + dv; \
    float s = (v >= 1.0f) ? 1.0f : 0.0f; \
    (O) = s + (X0); \
    v = (v >= 1.0f) ? 0.0f : v; \
    xm1 = (X0); }

#define Q4(BV, NX, O) \
    STEP(BV.x, BV.y, O.x) STEP(BV.y, BV.z, O.y) \
    STEP(BV.z, BV.w, O.z) STEP(BV.w, NX,   O.w)

// compute 32 elems from r0..r7; PEEK = x[tp+32]; optional full-line store burst
#define PHASE32(r0,r1,r2,r3,r4,r5,r6,r7, PEEK, TP, DOSTORE) { \
    f32x4 o0,o1,o2,o3,o4,o5,o6,o7; \
    Q4(r0, r1.x, o0) Q4(r1, r2.x, o1) Q4(r2, r3.x, o2) Q4(r3, r4.x, o3) \
    Q4(r4, r5.x, o4) Q4(r5, r6.x, o5) Q4(r6, r7.x, o6) Q4(r7, PEEK, o7) \
    if (DOSTORE) { \
        f32x4* _q = (f32x4*)(outr + (TP)); \
        _q[0]=o0; _q[1]=o1; _q[2]=o2; _q[3]=o3; \
        _q[4]=o4; _q[5]=o5; _q[6]=o6; _q[7]=o7; } }

// load one 32-elem phase (8 x float4); TP < 0 (k==0 lookback) -> zeros
#define LOADPH(r0,r1,r2,r3,r4,r5,r6,r7, TP) \
    if ((TP) >= 0) { const f32x4* _p = xr4 + ((TP) >> 2); \
        r0=_p[0]; r1=_p[1]; r2=_p[2]; r3=_p[3]; \
        r4=_p[4]; r5=_p[5]; r6=_p[6]; r7=_p[7]; } \
    else { r0=Z; r1=Z; r2=Z; r3=Z; r4=Z; r5=Z; r6=Z; r7=Z; }

__global__ __launch_bounds__(256) void cpe_lif_kernel(
    const float* __restrict__ x, const float* __restrict__ w,
    const float* __restrict__ cb, const float* __restrict__ gamma,
    const float* __restrict__ beta, const float* __restrict__ rmean,
    const float* __restrict__ rvar, float* __restrict__ out)
{
#pragma clang fp contract(off)   // match np reference rounding op-for-op
    const int u   = blockIdx.x * blockDim.x + threadIdx.x;
    const int row = u >> 5;          // / K_
    const int k   = u & (K_ - 1);
    const int ch  = row & (C_ - 1);

    // Per-channel constants, numpy-port op order (all fp32, correctly rounded).
    const float w0 = w[ch * 3 + 0], w1 = w[ch * 3 + 1], w2 = w[ch * 3 + 2];
    const float bb = cb[ch];
    const float sq  = sqrtf(rvar[ch] + 1e-5f);
    const float rs  = 1.0f / sq;
    const float inv = gamma[ch] * rs;
    const float add = beta[ch] - rmean[ch] * inv;

    const float*  xr  = x + (size_t)row * T_;
    const f32x4*  xr4 = (const f32x4*)xr;
    float* outr = out + (size_t)row * T_;

    const int t0 = k * CHUNK;
    const int ts = t0 - LOOK;            // <= 0 for k in {0,1}

    // Conv left halo: ts <= 0 -> window starts at t=0 whose halo is the zero pad.
    float xm1 = (ts <= 0) ? 0.0f : xr[ts - 1];
    const float xn = (k == K_ - 1) ? 0.0f : xr[t0 + CHUNK];    // right halo peek
    float v = 0.0f;

    f32x4 Z; Z.x = Z.y = Z.z = Z.w = 0.0f;
    f32x4 a0,a1,a2,a3,a4,a5,a6,a7;
    f32x4 b0,b1,b2,b3,b4,b5,b6,b7;
    f32x4 d0,d1,d2,d3,d4,d5,d6,d7;

    // Prologue: 3 phases of loads in flight (96 elements).
    LOADPH(a0,a1,a2,a3,a4,a5,a6,a7, ts)        // P0 (lookback)
    LOADPH(b0,b1,b2,b3,b4,b5,b6,b7, ts + 32)   // P1 (lookback)
    LOADPH(d0,d1,d2,d3,d4,d5,d6,d7, t0)        // P2 (output)

    // P0 (lookback, no store; k==0 skips: zeros, v must stay 0)
    if (k > 0) { PHASE32(a0,a1,a2,a3,a4,a5,a6,a7, b0.x, ts, false) }
    LOADPH(a0,a1,a2,a3,a4,a5,a6,a7, t0 + 32)   // P3 -> A

    // P1 (lookback, no store)
    if (k > 0) { PHASE32(b0,b1,b2,b3,b4,b5,b6,b7, d0.x, ts + 32, false) }

    // P2, P3 (t = t0 .. t0+63): store
    PHASE32(d0,d1,d2,d3,d4,d5,d6,d7, a0.x, t0,      true)
    PHASE32(a0,a1,a2,a3,a4,a5,a6,a7, xn,   t0 + 32, true)
}

extern "C" void kernel_launch(void* const* d_in, const int* in_sizes, int n_in,
                              void* d_out, int out_size, void* d_ws, size_t ws_size,
                              hipStream_t stream) {
    const float* x     = (const float*)d_in[0];
    const float* w     = (const float*)d_in[1];
    const float* cb    = (const float*)d_in[2];
    const float* gamma = (const float*)d_in[3];
    const float* beta  = (const float*)d_in[4];
    const float* rmean = (const float*)d_in[5];
    const float* rvar  = (const float*)d_in[6];
    float* out = (float*)d_out;

    const int total = B_ * C_ * K_;                    // 262144 threads
    const int block = 256;
    const int grid  = (total + block - 1) / block;     // 1024 blocks -> 4 wg/CU
    cpe_lif_kernel<<<grid, block, 0, stream>>>(x, w, cb, gamma, beta, rmean, rvar, out);
}

// Round 7
// 47.132 us; speedup vs baseline: 2.7512x; 1.0016x over previous
//
#include <hip/hip_runtime.h>

typedef float f32x4 __attribute__((ext_vector_type(4)));

// Problem constants: x [B,C,T] fp32 -> out [B,C,T] fp32.
#define B_ 32
#define C_ 256
#define T_ 2048
#define CHUNK 64
#define K_ 32          // chunks per row
#define LOOK 64        // warm-start lookback (bitwise-exact, proven R2/R3/R5/R6)

// One thread per (row, chunk). 4 phases x 32 elements = LOOK + CHUNK.
// Triple-buffered register pipeline + full-line (128 B) burst stores.
// R5 lesson: plain stores, NOT nontemporal (L2 write-combining needed).
// R6 lesson: VGPR=60 proved the compiler SANK the prefetch loads to their
// uses (24 live f32x4 needs >=96 VGPR), killing MLP. sched_barrier(0)
// fences after each load cluster pin the issue points.

#define SCHED_FENCE __builtin_amdgcn_sched_barrier(0)

#define STEP(X0, XP1, O) { \
    float y = w0 * xm1;  y = y + w1 * (X0);  y = y + w2 * (XP1); \
    y = y + bb;  y = y * inv;  y = y + add; \
    float dv = (y - v) * 0.5f;  v = v + dv; \
    float s = (v >= 1.0f) ? 1.0f : 0.0f; \
    (O) = s + (X0); \
    v = (v >= 1.0f) ? 0.0f : v; \
    xm1 = (X0); }

#define Q4(BV, NX, O) \
    STEP(BV.x, BV.y, O.x) STEP(BV.y, BV.z, O.y) \
    STEP(BV.z, BV.w, O.z) STEP(BV.w, NX,   O.w)

// compute 32 elems from r0..r7; PEEK = x[tp+32]; optional full-line store burst
#define PHASE32(r0,r1,r2,r3,r4,r5,r6,r7, PEEK, TP, DOSTORE) { \
    f32x4 o0,o1,o2,o3,o4,o5,o6,o7; \
    Q4(r0, r1.x, o0) Q4(r1, r2.x, o1) Q4(r2, r3.x, o2) Q4(r3, r4.x, o3) \
    Q4(r4, r5.x, o4) Q4(r5, r6.x, o5) Q4(r6, r7.x, o6) Q4(r7, PEEK, o7) \
    if (DOSTORE) { \
        f32x4* _q = (f32x4*)(outr + (TP)); \
        _q[0]=o0; _q[1]=o1; _q[2]=o2; _q[3]=o3; \
        _q[4]=o4; _q[5]=o5; _q[6]=o6; _q[7]=o7; } }

// load one 32-elem phase (8 x float4); TP < 0 (k==0 lookback) -> zeros
#define LOADPH(r0,r1,r2,r3,r4,r5,r6,r7, TP) \
    if ((TP) >= 0) { const f32x4* _p = xr4 + ((TP) >> 2); \
        r0=_p[0]; r1=_p[1]; r2=_p[2]; r3=_p[3]; \
        r4=_p[4]; r5=_p[5]; r6=_p[6]; r7=_p[7]; } \
    else { r0=Z; r1=Z; r2=Z; r3=Z; r4=Z; r5=Z; r6=Z; r7=Z; }

__global__ __launch_bounds__(256) void cpe_lif_kernel(
    const float* __restrict__ x, const float* __restrict__ w,
    const float* __restrict__ cb, const float* __restrict__ gamma,
    const float* __restrict__ beta, const float* __restrict__ rmean,
    const float* __restrict__ rvar, float* __restrict__ out)
{
#pragma clang fp contract(off)   // match np reference rounding op-for-op
    const int u   = blockIdx.x * blockDim.x + threadIdx.x;
    const int row = u >> 5;          // / K_
    const int k   = u & (K_ - 1);
    const int ch  = row & (C_ - 1);

    // Per-channel constants, numpy-port op order (all fp32, correctly rounded).
    const float w0 = w[ch * 3 + 0], w1 = w[ch * 3 + 1], w2 = w[ch * 3 + 2];
    const float bb = cb[ch];
    const float sq  = sqrtf(rvar[ch] + 1e-5f);
    const float rs  = 1.0f / sq;
    const float inv = gamma[ch] * rs;
    const float add = beta[ch] - rmean[ch] * inv;

    const float*  xr  = x + (size_t)row * T_;
    const f32x4*  xr4 = (const f32x4*)xr;
    float* outr = out + (size_t)row * T_;

    const int t0 = k * CHUNK;
    const int ts = t0 - LOOK;            // <= 0 for k in {0,1}

    // Conv left halo: ts <= 0 -> window starts at t=0 whose halo is the zero pad.
    float xm1 = (ts <= 0) ? 0.0f : xr[ts - 1];
    const float xn = (k == K_ - 1) ? 0.0f : xr[t0 + CHUNK];    // right halo peek
    float v = 0.0f;

    f32x4 Z; Z.x = Z.y = Z.z = Z.w = 0.0f;
    f32x4 a0,a1,a2,a3,a4,a5,a6,a7;
    f32x4 b0,b1,b2,b3,b4,b5,b6,b7;
    f32x4 d0,d1,d2,d3,d4,d5,d6,d7;

    // Prologue: 3 phases of loads ISSUED HERE (96 elements, 24 dwordx4).
    LOADPH(a0,a1,a2,a3,a4,a5,a6,a7, ts)        // P0 (lookback)
    LOADPH(b0,b1,b2,b3,b4,b5,b6,b7, ts + 32)   // P1 (lookback)
    LOADPH(d0,d1,d2,d3,d4,d5,d6,d7, t0)        // P2 (output)
    SCHED_FENCE;   // loads may not sink below; compute may not hoist above

    // P0 (lookback, no store; k==0 skips: zeros, v must stay 0)
    if (k > 0) { PHASE32(a0,a1,a2,a3,a4,a5,a6,a7, b0.x, ts, false) }
    SCHED_FENCE;
    LOADPH(a0,a1,a2,a3,a4,a5,a6,a7, t0 + 32)   // P3 -> A, issued before P1 compute
    SCHED_FENCE;

    // P1 (lookback, no store)
    if (k > 0) { PHASE32(b0,b1,b2,b3,b4,b5,b6,b7, d0.x, ts + 32, false) }

    // P2, P3 (t = t0 .. t0+63): store
    PHASE32(d0,d1,d2,d3,d4,d5,d6,d7, a0.x, t0,      true)
    PHASE32(a0,a1,a2,a3,a4,a5,a6,a7, xn,   t0 + 32, true)
}

extern "C" void kernel_launch(void* const* d_in, const int* in_sizes, int n_in,
                              void* d_out, int out_size, void* d_ws, size_t ws_size,
                              hipStream_t stream) {
    const float* x     = (const float*)d_in[0];
    const float* w     = (const float*)d_in[1];
    const float* cb    = (const float*)d_in[2];
    const float* gamma = (const float*)d_in[3];
    const float* beta  = (const float*)d_in[4];
    const float* rmean = (const float*)d_in[5];
    const float* rvar  = (const float*)d_in[6];
    float* out = (float*)d_out;

    const int total = B_ * C_ * K_;                    // 262144 threads
    const int block = 256;
    const int grid  = (total + block - 1) / block;     // 1024 blocks -> 4 wg/CU
    cpe_lif_kernel<<<grid, block, 0, stream>>>(x, w, cb, gamma, beta, rmean, rvar, out);
}

// Round 8
// 40.241 us; speedup vs baseline: 3.2223x; 1.1712x over previous
//
#include <hip/hip_runtime.h>

typedef float f32x4 __attribute__((ext_vector_type(4)));

// Problem constants: x [B,C,T] fp32 -> out [B,C,T] fp32.
#define B_ 32
#define C_ 256
#define T_ 2048
#define RPB 4          // rows per block (one per wave)

// R5 lesson: plain stores (L2 write-combining), never nontemporal.
// R7 lesson: strided 64-line-per-instruction global loads cap at ~2.6 TB/s
// regardless of TLP -> stage rows in LDS with contiguous global_load_lds,
// scan from LDS. XOR-swizzle granules within 128B blocks (applied as a lane
// permutation of the GLOBAL source; LDS dest stays linear) so per-lane
// ds_read_b128 rows spread uniformly over the 8 bank groups.

#define STEP(X0, XP1, O) { \
    float y = w0 * xm1;  y = y + w1 * (X0);  y = y + w2 * (XP1); \
    y = y + bb;  y = y * inv;  y = y + add; \
    float dv = (y - v) * 0.5f;  v = v + dv; \
    float s = (v >= 1.0f) ? 1.0f : 0.0f; \
    (O) = s + (X0); \
    v = (v >= 1.0f) ? 0.0f : v; \
    xm1 = (X0); }

#define Q4(BV, NX, O) \
    STEP(BV.x, BV.y, O.x) STEP(BV.y, BV.z, O.y) \
    STEP(BV.z, BV.w, O.z) STEP(BV.w, NX,   O.w)

// One phase: 8 granules (32 elems) starting at granule G (G % 8 == 0).
// Granule G+j lives at LDS granule (G + (j ^ m)), m = (G>>3)&7.
#define PH(G, PEEK, DOSTORE) { \
    const int _m = (((G) >> 3) & 7); \
    const float* _bp = wl + ((G) << 2); \
    f32x4 r0 = *(const f32x4*)(_bp + ((0 ^ _m) << 2)); \
    f32x4 r1 = *(const f32x4*)(_bp + ((1 ^ _m) << 2)); \
    f32x4 r2 = *(const f32x4*)(_bp + ((2 ^ _m) << 2)); \
    f32x4 r3 = *(const f32x4*)(_bp + ((3 ^ _m) << 2)); \
    f32x4 r4 = *(const f32x4*)(_bp + ((4 ^ _m) << 2)); \
    f32x4 r5 = *(const f32x4*)(_bp + ((5 ^ _m) << 2)); \
    f32x4 r6 = *(const f32x4*)(_bp + ((6 ^ _m) << 2)); \
    f32x4 r7 = *(const f32x4*)(_bp + ((7 ^ _m) << 2)); \
    f32x4 o0,o1,o2,o3,o4,o5,o6,o7; \
    Q4(r0, r1.x, o0) Q4(r1, r2.x, o1) Q4(r2, r3.x, o2) Q4(r3, r4.x, o3) \
    Q4(r4, r5.x, o4) Q4(r5, r6.x, o5) Q4(r6, r7.x, o6) Q4(r7, (PEEK), o7) \
    if (DOSTORE) { \
        f32x4* _q = (f32x4*)(outr + ((G) << 2)); \
        _q[0]=o0; _q[1]=o1; _q[2]=o2; _q[3]=o3; \
        _q[4]=o4; _q[5]=o5; _q[6]=o6; _q[7]=o7; } }

__device__ __forceinline__ int swzg(int g) { return g ^ ((g >> 3) & 7); }

typedef __attribute__((address_space(1))) const unsigned int GBUF;
typedef __attribute__((address_space(3))) unsigned int LBUF;

__global__ __launch_bounds__(256, 5) void cpe_lif_kernel(
    const float* __restrict__ x, const float* __restrict__ w,
    const float* __restrict__ cb, const float* __restrict__ gamma,
    const float* __restrict__ beta, const float* __restrict__ rmean,
    const float* __restrict__ rvar, float* __restrict__ out)
{
#pragma clang fp contract(off)   // match np reference rounding op-for-op
    __shared__ __align__(16) float lds[RPB * T_];   // 32 KiB: 4 rows

    const int tid = threadIdx.x;
    const int wid = tid >> 6;          // wave = row within block
    const int l   = tid & 63;          // lane = chunk within row (CHUNK=32)
    const int row = blockIdx.x * RPB + wid;
    const int ch  = row & (C_ - 1);

    // Per-channel constants, numpy-port op order (all fp32, correctly rounded).
    const float w0 = w[ch * 3 + 0], w1 = w[ch * 3 + 1], w2 = w[ch * 3 + 2];
    const float bb = cb[ch];
    const float sq  = sqrtf(rvar[ch] + 1e-5f);
    const float rs  = 1.0f / sq;
    const float inv = gamma[ch] * rs;
    const float add = beta[ch] - rmean[ch] * inv;

    const float* xr   = x + (size_t)row * T_;
    float*       outr = out + (size_t)row * T_;
    float*       wl   = lds + wid * T_;            // this wave's 8 KB slice

    // ---- Stage row -> LDS: 8 x 1KB contiguous global_load_lds.
    // Source lane-permuted so that LDS granule s holds global granule swzg(s).
    const int lsrc = l ^ ((l >> 3) & 7);
    #pragma unroll
    for (int i = 0; i < 8; ++i)
        __builtin_amdgcn_global_load_lds((GBUF*)(xr + i * 256 + (lsrc << 2)),
                                         (LBUF*)(wl + i * 256), 16, 0, 0);

    asm volatile("s_waitcnt vmcnt(0)" ::: "memory");   // own loads only; no barrier
    __builtin_amdgcn_sched_barrier(0);

    // ---- Per-lane scan: lookback (<=64) + own 32 elems. v exact for lanes 0..2.
    float v = 0.0f;
    float xm1 = 0.0f;
    if (l >= 3) {                       // x[32l-65]: granule 8l-17, sub 3
        const int g = 8 * l - 17;
        xm1 = wl[(swzg(g) << 2) + 3];
    }

    if (l >= 2) {                       // lookback phase A: elems [32l-64, 32l-32)
        const int G = 8 * l - 16;
        const float peek = wl[swzg(G + 8) << 2];
        PH(G, peek, false)
    }
    if (l >= 1) {                       // lookback phase B: elems [32l-32, 32l)
        const int G = 8 * l - 8;
        const float peek = wl[swzg(G + 8) << 2];
        PH(G, peek, false)
    }
    {                                   // own chunk: elems [32l, 32l+32), store
        const int G = 8 * l;
        const float peek = (l == 63) ? 0.0f : wl[swzg(G + 8) << 2];
        PH(G, peek, true)
    }
}

extern "C" void kernel_launch(void* const* d_in, const int* in_sizes, int n_in,
                              void* d_out, int out_size, void* d_ws, size_t ws_size,
                              hipStream_t stream) {
    const float* x     = (const float*)d_in[0];
    const float* w     = (const float*)d_in[1];
    const float* cb    = (const float*)d_in[2];
    const float* gamma = (const float*)d_in[3];
    const float* beta  = (const float*)d_in[4];
    const float* rmean = (const float*)d_in[5];
    const float* rvar  = (const float*)d_in[6];
    float* out = (float*)d_out;

    const int grid = (B_ * C_) / RPB;                  // 2048 blocks x 256 thr
    cpe_lif_kernel<<<grid, 256, 0, stream>>>(x, w, cb, gamma, beta, rmean, rvar, out);
}

// Round 9
// 39.654 us; speedup vs baseline: 3.2700x; 1.0148x over previous
//
#include <hip/hip_runtime.h>

typedef float f32x4 __attribute__((ext_vector_type(4)));

// Problem constants: x [B,C,T] fp32 -> out [B,C,T] fp32.
#define B_ 32
#define C_ 256
#define T_ 2048
#define RPB 2          // rows per block (one per wave) -> 128 threads, 16 KiB LDS

// R5: plain stores (L2 write-combining), never nontemporal.
// R7: strided global loads cap ~2.6 TB/s -> stage rows via global_load_lds.
// R8: XOR-swizzled b128 LDS reads are conflict-free (983k conflicts were
//     entirely the 4 narrow b32 reads/wave hitting 8 banks); occupancy 27%
//     (32 KiB blocks) was the limiter -> 2-wave/16 KiB blocks + no b32 reads.

#define STEP(X0, XP1, O) { \
    float y = w0 * xm1;  y = y + w1 * (X0);  y = y + w2 * (XP1); \
    y = y + bb;  y = y * inv;  y = y + add; \
    float dv = (y - v) * 0.5f;  v = v + dv; \
    float s = (v >= 1.0f) ? 1.0f : 0.0f; \
    (O) = s + (X0); \
    v = (v >= 1.0f) ? 0.0f : v; \
    xm1 = (X0); }

#define Q4(BV, NX, O) \
    STEP(BV.x, BV.y, O.x) STEP(BV.y, BV.z, O.y) \
    STEP(BV.z, BV.w, O.z) STEP(BV.w, NX,   O.w)

// Load one 8-granule phase from swizzled LDS. GC = base granule (multiple of 8).
// Global granule GC+j lives at LDS granule GC + (j ^ m), m = (GC>>3)&7.
#define LDPH(p0,p1,p2,p3,p4,p5,p6,p7, GC) { \
    const int _m = ((GC) >> 3) & 7; \
    const float* _bp = wl + ((GC) << 2); \
    p0 = *(const f32x4*)(_bp + ((0 ^ _m) << 2)); \
    p1 = *(const f32x4*)(_bp + ((1 ^ _m) << 2)); \
    p2 = *(const f32x4*)(_bp + ((2 ^ _m) << 2)); \
    p3 = *(const f32x4*)(_bp + ((3 ^ _m) << 2)); \
    p4 = *(const f32x4*)(_bp + ((4 ^ _m) << 2)); \
    p5 = *(const f32x4*)(_bp + ((5 ^ _m) << 2)); \
    p6 = *(const f32x4*)(_bp + ((6 ^ _m) << 2)); \
    p7 = *(const f32x4*)(_bp + ((7 ^ _m) << 2)); }

// Compute-only phase (lookback): outputs dead, chain lives through v/xm1.
#define PHC(r0,r1,r2,r3,r4,r5,r6,r7, PEEK) { \
    f32x4 _d; \
    Q4(r0, r1.x, _d) Q4(r1, r2.x, _d) Q4(r2, r3.x, _d) Q4(r3, r4.x, _d) \
    Q4(r4, r5.x, _d) Q4(r5, r6.x, _d) Q4(r6, r7.x, _d) Q4(r7, (PEEK), _d) }

__device__ __forceinline__ int swzg(int g) { return g ^ ((g >> 3) & 7); }

typedef __attribute__((address_space(1))) const unsigned int GBUF;
typedef __attribute__((address_space(3))) unsigned int LBUF;

__global__ __launch_bounds__(128, 4) void cpe_lif_kernel(
    const float* __restrict__ x, const float* __restrict__ w,
    const float* __restrict__ cb, const float* __restrict__ gamma,
    const float* __restrict__ beta, const float* __restrict__ rmean,
    const float* __restrict__ rvar, float* __restrict__ out)
{
#pragma clang fp contract(off)   // match np reference rounding op-for-op
    __shared__ __align__(16) float lds[RPB * T_];   // 16 KiB: 2 rows

    const int tid = threadIdx.x;
    const int wid = tid >> 6;          // wave = row within block
    const int l   = tid & 63;          // lane = chunk within row (CHUNK=32)
    const int row = blockIdx.x * RPB + wid;
    const int ch  = row & (C_ - 1);

    // Per-channel constants, numpy-port op order (all fp32, correctly rounded).
    const float w0 = w[ch * 3 + 0], w1 = w[ch * 3 + 1], w2 = w[ch * 3 + 2];
    const float bb = cb[ch];
    const float sq  = sqrtf(rvar[ch] + 1e-5f);
    const float rs  = 1.0f / sq;
    const float inv = gamma[ch] * rs;
    const float add = beta[ch] - rmean[ch] * inv;

    const float* xr   = x + (size_t)row * T_;
    float*       outr = out + (size_t)row * T_;
    float*       wl   = lds + wid * T_;            // this wave's 8 KB slice

    // ---- Stage row -> LDS: 8 x 1KB contiguous global_load_lds; source is
    // lane-permuted so LDS granule s holds global granule swzg(s) (rule #21).
    const int lsrc = l ^ ((l >> 3) & 7);
    #pragma unroll
    for (int i = 0; i < 8; ++i)
        __builtin_amdgcn_global_load_lds((GBUF*)(xr + i * 256 + (lsrc << 2)),
                                         (LBUF*)(wl + i * 256), 16, 0, 0);

    asm volatile("s_waitcnt vmcnt(0)" ::: "memory");   // own loads only; no barrier
    __builtin_amdgcn_sched_barrier(0);

    // ---- Per-lane scan: 64-elem lookback + own 32 elems. Exact for lanes 0..2.
    const int G2  = 8 * l;                         // own-chunk base granule
    const int G1c = (l >= 1) ? G2 - 8  : 0;        // lookback B (clamped)
    const int G0c = (l >= 2) ? G2 - 16 : 0;        // lookback A (clamped)

    // xm1 seed: word 3 of global granule 8l-17 (b128-class read, no b32).
    const int gt = (l >= 3) ? (G2 - 17) : 0;
    const f32x4 tail = *(const f32x4*)(wl + (swzg(gt) << 2));
    float xm1 = (l >= 3) ? tail.w : 0.0f;
    float v = 0.0f;

    f32x4 a0,a1,a2,a3,a4,a5,a6,a7;
    f32x4 b0,b1,b2,b3,b4,b5,b6,b7;
    f32x4 c0,c1,c2,c3,c4,c5,c6,c7;

    LDPH(a0,a1,a2,a3,a4,a5,a6,a7, G0c)
    LDPH(b0,b1,b2,b3,b4,b5,b6,b7, G1c)
    c0 = *(const f32x4*)(wl + ((G2 + (0 ^ (l & 7))) << 2));   // peek for phase B

    if (l >= 2) { PHC(a0,a1,a2,a3,a4,a5,a6,a7, b0.x) }        // peek(A)=b0.x

    // load rest of own phase + own-peek granule during/after phase A
    {
        const int _m = l & 7;
        const float* _bp = wl + (G2 << 2);
        c1 = *(const f32x4*)(_bp + ((1 ^ _m) << 2));
        c2 = *(const f32x4*)(_bp + ((2 ^ _m) << 2));
        c3 = *(const f32x4*)(_bp + ((3 ^ _m) << 2));
        c4 = *(const f32x4*)(_bp + ((4 ^ _m) << 2));
        c5 = *(const f32x4*)(_bp + ((5 ^ _m) << 2));
        c6 = *(const f32x4*)(_bp + ((6 ^ _m) << 2));
        c7 = *(const f32x4*)(_bp + ((7 ^ _m) << 2));
    }
    const int gp = (l < 63) ? (G2 + 8) : 0;        // own-peek: granule 8(l+1)
    const f32x4 pk = *(const f32x4*)(wl + (swzg(gp) << 2));
    const float peekOwn = (l == 63) ? 0.0f : pk.x;

    if (l >= 1) { PHC(b0,b1,b2,b3,b4,b5,b6,b7, c0.x) }        // peek(B)=c0.x

    // own chunk: elems [32l, 32l+32), store full 128 B line burst
    f32x4 o0,o1,o2,o3,o4,o5,o6,o7;
    Q4(c0, c1.x, o0) Q4(c1, c2.x, o1) Q4(c2, c3.x, o2) Q4(c3, c4.x, o3)
    Q4(c4, c5.x, o4) Q4(c5, c6.x, o5) Q4(c6, c7.x, o6) Q4(c7, peekOwn, o7)
    {
        f32x4* _q = (f32x4*)(outr + (G2 << 2));
        _q[0]=o0; _q[1]=o1; _q[2]=o2; _q[3]=o3;
        _q[4]=o4; _q[5]=o5; _q[6]=o6; _q[7]=o7;
    }
}

extern "C" void kernel_launch(void* const* d_in, const int* in_sizes, int n_in,
                              void* d_out, int out_size, void* d_ws, size_t ws_size,
                              hipStream_t stream) {
    const float* x     = (const float*)d_in[0];
    const float* w     = (const float*)d_in[1];
    const float* cb    = (const float*)d_in[2];
    const float* gamma = (const float*)d_in[3];
    const float* beta  = (const float*)d_in[4];
    const float* rmean = (const float*)d_in[5];
    const float* rvar  = (const float*)d_in[6];
    float* out = (float*)d_out;

    const int grid = (B_ * C_) / RPB;              // 4096 blocks x 128 threads
    cpe_lif_kernel<<<grid, 128, 0, stream>>>(x, w, cb, gamma, beta, rmean, rvar, out);
}

// Round 10
// 31.199 us; speedup vs baseline: 4.1562x; 1.2710x over previous
//
#include <hip/hip_runtime.h>

typedef float f32x4 __attribute__((ext_vector_type(4)));

// Problem constants: x [B,C,T] fp32 -> out [B,C,T] fp32.
#define B_ 32
#define C_ 256
#define T_ 2048
#define RPB 2          // rows per block (one per wave) -> 128 threads, 16 KiB LDS

// R5: plain stores (L2 write-combining), never nontemporal.
// R7: strided global loads cap ~2.6 TB/s -> stage rows via global_load_lds.
// R8: XOR-swizzled b128 LDS reads ~conflict-free; occupancy not the limiter.
// R9: residency falsified as limiter (16 KiB blocks, same 40 us). Last
//     scattered vmem pattern = stores (64 lines/instr). R10: round-trip the
//     outputs through LDS (same swzg bijection) and store fully coalesced
//     (1 KB contiguous per instruction, 8 lines/instr).

#define STEP(X0, XP1, O) { \
    float y = w0 * xm1;  y = y + w1 * (X0);  y = y + w2 * (XP1); \
    y = y + bb;  y = y * inv;  y = y + add; \
    float dv = (y - v) * 0.5f;  v = v + dv; \
    float s = (v >= 1.0f) ? 1.0f : 0.0f; \
    (O) = s + (X0); \
    v = (v >= 1.0f) ? 0.0f : v; \
    xm1 = (X0); }

#define Q4(BV, NX, O) \
    STEP(BV.x, BV.y, O.x) STEP(BV.y, BV.z, O.y) \
    STEP(BV.z, BV.w, O.z) STEP(BV.w, NX,   O.w)

// Load one 8-granule phase from swizzled LDS. GC = base granule (multiple of 8).
// Global granule GC+j lives at LDS granule GC + (j ^ m), m = (GC>>3)&7.
#define LDPH(p0,p1,p2,p3,p4,p5,p6,p7, GC) { \
    const int _m = ((GC) >> 3) & 7; \
    const float* _bp = wl + ((GC) << 2); \
    p0 = *(const f32x4*)(_bp + ((0 ^ _m) << 2)); \
    p1 = *(const f32x4*)(_bp + ((1 ^ _m) << 2)); \
    p2 = *(const f32x4*)(_bp + ((2 ^ _m) << 2)); \
    p3 = *(const f32x4*)(_bp + ((3 ^ _m) << 2)); \
    p4 = *(const f32x4*)(_bp + ((4 ^ _m) << 2)); \
    p5 = *(const f32x4*)(_bp + ((5 ^ _m) << 2)); \
    p6 = *(const f32x4*)(_bp + ((6 ^ _m) << 2)); \
    p7 = *(const f32x4*)(_bp + ((7 ^ _m) << 2)); }

// Compute-only phase (lookback): outputs dead, chain lives through v/xm1.
#define PHC(r0,r1,r2,r3,r4,r5,r6,r7, PEEK) { \
    f32x4 _d; \
    Q4(r0, r1.x, _d) Q4(r1, r2.x, _d) Q4(r2, r3.x, _d) Q4(r3, r4.x, _d) \
    Q4(r4, r5.x, _d) Q4(r5, r6.x, _d) Q4(r6, r7.x, _d) Q4(r7, (PEEK), _d) }

__device__ __forceinline__ int swzg(int g) { return g ^ ((g >> 3) & 7); }

typedef __attribute__((address_space(1))) const unsigned int GBUF;
typedef __attribute__((address_space(3))) unsigned int LBUF;

__global__ __launch_bounds__(128, 4) void cpe_lif_kernel(
    const float* __restrict__ x, const float* __restrict__ w,
    const float* __restrict__ cb, const float* __restrict__ gamma,
    const float* __restrict__ beta, const float* __restrict__ rmean,
    const float* __restrict__ rvar, float* __restrict__ out)
{
#pragma clang fp contract(off)   // match np reference rounding op-for-op
    __shared__ __align__(16) float lds[RPB * T_];   // 16 KiB: 2 rows

    const int tid = threadIdx.x;
    const int wid = tid >> 6;          // wave = row within block
    const int l   = tid & 63;          // lane = chunk within row (CHUNK=32)
    const int row = blockIdx.x * RPB + wid;
    const int ch  = row & (C_ - 1);

    // Per-channel constants, numpy-port op order (all fp32, correctly rounded).
    const float w0 = w[ch * 3 + 0], w1 = w[ch * 3 + 1], w2 = w[ch * 3 + 2];
    const float bb = cb[ch];
    const float sq  = sqrtf(rvar[ch] + 1e-5f);
    const float rs  = 1.0f / sq;
    const float inv = gamma[ch] * rs;
    const float add = beta[ch] - rmean[ch] * inv;

    const float* xr   = x + (size_t)row * T_;
    float*       outr = out + (size_t)row * T_;
    float*       wl   = lds + wid * T_;            // this wave's 8 KB slice

    // ---- Stage row -> LDS: 8 x 1KB contiguous global_load_lds; source is
    // lane-permuted so LDS granule s holds global granule swzg(s) (rule #21).
    const int lsrc = l ^ ((l >> 3) & 7);
    #pragma unroll
    for (int i = 0; i < 8; ++i)
        __builtin_amdgcn_global_load_lds((GBUF*)(xr + i * 256 + (lsrc << 2)),
                                         (LBUF*)(wl + i * 256), 16, 0, 0);

    asm volatile("s_waitcnt vmcnt(0)" ::: "memory");   // own loads only; no barrier
    __builtin_amdgcn_sched_barrier(0);

    // ---- Per-lane scan: 64-elem lookback + own 32 elems. Exact for lanes 0..2.
    const int G2  = 8 * l;                         // own-chunk base granule
    const int G1c = (l >= 1) ? G2 - 8  : 0;        // lookback B (clamped)
    const int G0c = (l >= 2) ? G2 - 16 : 0;        // lookback A (clamped)

    // xm1 seed: word 3 of global granule 8l-17 (b128-class read).
    const int gt = (l >= 3) ? (G2 - 17) : 0;
    const f32x4 tail = *(const f32x4*)(wl + (swzg(gt) << 2));
    float xm1 = (l >= 3) ? tail.w : 0.0f;
    float v = 0.0f;

    f32x4 a0,a1,a2,a3,a4,a5,a6,a7;
    f32x4 b0,b1,b2,b3,b4,b5,b6,b7;
    f32x4 c0,c1,c2,c3,c4,c5,c6,c7;

    LDPH(a0,a1,a2,a3,a4,a5,a6,a7, G0c)
    LDPH(b0,b1,b2,b3,b4,b5,b6,b7, G1c)
    c0 = *(const f32x4*)(wl + ((G2 + (0 ^ (l & 7))) << 2));   // peek for phase B

    if (l >= 2) { PHC(a0,a1,a2,a3,a4,a5,a6,a7, b0.x) }        // peek(A)=b0.x

    {   // rest of own phase
        const int _m = l & 7;
        const float* _bp = wl + (G2 << 2);
        c1 = *(const f32x4*)(_bp + ((1 ^ _m) << 2));
        c2 = *(const f32x4*)(_bp + ((2 ^ _m) << 2));
        c3 = *(const f32x4*)(_bp + ((3 ^ _m) << 2));
        c4 = *(const f32x4*)(_bp + ((4 ^ _m) << 2));
        c5 = *(const f32x4*)(_bp + ((5 ^ _m) << 2));
        c6 = *(const f32x4*)(_bp + ((6 ^ _m) << 2));
        c7 = *(const f32x4*)(_bp + ((7 ^ _m) << 2));
    }
    const int gp = (l < 63) ? (G2 + 8) : 0;        // own-peek: granule 8(l+1)
    const f32x4 pk = *(const f32x4*)(wl + (swzg(gp) << 2));
    const float peekOwn = (l == 63) ? 0.0f : pk.x;

    if (l >= 1) { PHC(b0,b1,b2,b3,b4,b5,b6,b7, c0.x) }        // peek(B)=c0.x

    // own chunk: elems [32l, 32l+32)
    f32x4 o0,o1,o2,o3,o4,o5,o6,o7;
    Q4(c0, c1.x, o0) Q4(c1, c2.x, o1) Q4(c2, c3.x, o2) Q4(c3, c4.x, o3)
    Q4(c4, c5.x, o4) Q4(c5, c6.x, o5) Q4(c6, c7.x, o6) Q4(c7, peekOwn, o7)

    // ---- Writeback to LDS (same swzg layout; x fully consumed by this wave;
    // per-wave in-order DS pipe makes this safe without a barrier), then
    // linear readback + fully-coalesced 1 KB global stores.
    {
        const int m8 = l & 7;
        float* wb = wl + (G2 << 2);
        *(f32x4*)(wb + ((0 ^ m8) << 2)) = o0;
        *(f32x4*)(wb + ((1 ^ m8) << 2)) = o1;
        *(f32x4*)(wb + ((2 ^ m8) << 2)) = o2;
        *(f32x4*)(wb + ((3 ^ m8) << 2)) = o3;
        *(f32x4*)(wb + ((4 ^ m8) << 2)) = o4;
        *(f32x4*)(wb + ((5 ^ m8) << 2)) = o5;
        *(f32x4*)(wb + ((6 ^ m8) << 2)) = o6;
        *(f32x4*)(wb + ((7 ^ m8) << 2)) = o7;
    }
    #pragma unroll
    for (int i = 0; i < 8; ++i) {
        // global granule i*64 + l lives at LDS granule i*64 + lsrc
        const f32x4 rb = *(const f32x4*)(wl + ((i * 64 + lsrc) << 2));
        *(f32x4*)(outr + i * 256 + (l << 2)) = rb;   // lane-contiguous 1 KB
    }
}

extern "C" void kernel_launch(void* const* d_in, const int* in_sizes, int n_in,
                              void* d_out, int out_size, void* d_ws, size_t ws_size,
                              hipStream_t stream) {
    const float* x     = (const float*)d_in[0];
    const float* w     = (const float*)d_in[1];
    const float* cb    = (const float*)d_in[2];
    const float* gamma = (const float*)d_in[3];
    const float* beta  = (const float*)d_in[4];
    const float* rmean = (const float*)d_in[5];
    const float* rvar  = (const float*)d_in[6];
    float* out = (float*)d_out;

    const int grid = (B_ * C_) / RPB;              // 4096 blocks x 128 threads
    cpe_lif_kernel<<<grid, 128, 0, stream>>>(x, w, cb, gamma, beta, rmean, rvar, out);
}